// Round 5
// baseline (332.137 us; speedup 1.0000x reference)
//
#include <hip/hip_runtime.h>
#include <hip/hip_bf16.h>
#include <cstdint>

typedef __bf16 bf16_t;
typedef bf16_t bf16x8 __attribute__((ext_vector_type(8)));
typedef float f32x4 __attribute__((ext_vector_type(4)));

// B=4, S=4096, DIM=1024, H=16, HD=64, M=64
// QKV layout: [16384][3072] bf16, cols 0-1023 = Q', 1024-2047 = K', 2048-3071 = V

__device__ __forceinline__ void gload_lds16(const bf16_t* g, bf16_t* l) {
  __builtin_amdgcn_global_load_lds(
      (const __attribute__((address_space(1))) uint32_t*)g,
      (__attribute__((address_space(3))) uint32_t*)l, 16, 0, 0);
}

// ---------------- cast fp32 -> bf16 (vectorized, 8 elems/thread) ----------------
__global__ void cast_f32_bf16(const float* __restrict__ in, bf16_t* __restrict__ out, int n8) {
  int i = blockIdx.x * 256 + threadIdx.x;
  if (i < n8) {
    const f32x4* p = (const f32x4*)(in + (long)i * 8);
    f32x4 a = p[0], b = p[1];
    bf16x8 o;
#pragma unroll
    for (int j = 0; j < 4; ++j) { o[j] = (bf16_t)a[j]; o[j + 4] = (bf16_t)b[j]; }
    *(bf16x8*)(out + (long)i * 8) = o;
  }
}

__global__ void copy_f32(const float* __restrict__ in, float* __restrict__ out, int n) {
  int i = blockIdx.x * 256 + threadIdx.x;
  if (i < n) out[i] = in[i];
}

// ---------------- fold P into Wq/Wk:  WQP[h*64+m][k] = sum_d P[h][m][d]*W[h*64+d][k] ----------------
__global__ __launch_bounds__(256) void prep_wqk(
    const float* __restrict__ Wq, const float* __restrict__ bq,
    const float* __restrict__ Wk, const float* __restrict__ bk,
    const float* __restrict__ P,
    bf16_t* __restrict__ Wcat, float* __restrict__ bcat)
{
  int bid = blockIdx.x;
  int qk = bid >> 7, h = (bid >> 3) & 15, kt = bid & 7;
  const float* W = qk ? Wk : Wq;
  const float* bias = qk ? bk : bq;
  __shared__ float Pl[64 * 64];
  __shared__ float Wlt[128 * 68];
  int t = threadIdx.x;
  int k0 = kt * 128;
  for (int i = t * 4; i < 4096; i += 1024)
    *(f32x4*)&Pl[i] = *(const f32x4*)&P[h * 4096 + i];
  for (int fi = t; fi < 2048; fi += 256) {
    int row = fi >> 5;
    int c4 = fi & 31;
    f32x4 w = *(const f32x4*)&W[(long)(h * 64 + row) * 1024 + k0 + c4 * 4];
#pragma unroll
    for (int j = 0; j < 4; ++j) Wlt[(c4 * 4 + j) * 68 + row] = w[j];
  }
  __syncthreads();
  int kloc = t >> 1;
  int mh = (t & 1) * 32;
  for (int m = mh; m < mh + 32; ++m) {
    f32x4 s = {0.f, 0.f, 0.f, 0.f};
#pragma unroll
    for (int dd = 0; dd < 16; ++dd)
      s += (*(const f32x4*)&Pl[m * 64 + dd * 4]) * (*(const f32x4*)&Wlt[kloc * 68 + dd * 4]);
    float a = s[0] + s[1] + s[2] + s[3];
    Wcat[(long)(qk * 1024 + h * 64 + m) * 1024 + k0 + kloc] = (bf16_t)a;
  }
  if (kt == 0 && t < 64) {
    float a = 0.f;
    for (int d = 0; d < 64; ++d) a += Pl[t * 64 + d] * bias[h * 64 + d];
    bcat[qk * 1024 + h * 64 + t] = a;
  }
}

// ---------------- 256x256 GEMM, BK=64, 8 waves ----------------------------------
// r1 skeleton (stage-early, ONE __syncthreads per K-tile, compiler-scheduled).
// A staged via global_load_lds into swizzled LDS (double-buffered, 64KB).
// B (L2-resident) loaded DIRECTLY global->registers, prefetched one tile ahead.
// EPI=1: bf16 out via LDS-transposed vectorized epilogue, relu*0.125 for gcol<2048.
// EPI=2: fp32 out, direct stores.

#define LOADB(dst, KN) {                                                     \
  _Pragma("unroll") for (int ni = 0; ni < 4; ++ni) {                         \
    dst[ni][0] = *(const bf16x8*)(Bp + (long)ni * 16 * ldb + (KN));          \
    dst[ni][1] = *(const bf16x8*)(Bp + (long)ni * 16 * ldb + (KN) + 32);     \
  } }

#define TILE1(sAc, sAn, bC, bN, KN, STG) {                                              \
  bf16x8 afr[4][2];                                                                     \
  _Pragma("unroll") for (int mi = 0; mi < 4; ++mi) {                                    \
    afr[mi][0] = *(const bf16x8*)&sAc[abase + mi * 1024 + aoff0];                       \
    afr[mi][1] = *(const bf16x8*)&sAc[abase + mi * 1024 + aoff1];                       \
  }                                                                                     \
  if (STG) {                                                                            \
    gload_lds16(A + a_off[0] + (KN), &sAn[dst8]);                                       \
    gload_lds16(A + a_off[1] + (KN), &sAn[4096 + dst8]);                                \
    gload_lds16(A + a_off[2] + (KN), &sAn[8192 + dst8]);                                \
    gload_lds16(A + a_off[3] + (KN), &sAn[12288 + dst8]);                               \
    LOADB(bN, KN);                                                                      \
  }                                                                                     \
  __builtin_amdgcn_s_setprio(1);                                                        \
  _Pragma("unroll") for (int mi = 0; mi < 4; ++mi)                                      \
    _Pragma("unroll") for (int ni = 0; ni < 4; ++ni) {                                  \
      acc[mi][ni] = __builtin_amdgcn_mfma_f32_16x16x32_bf16(afr[mi][0], bC[ni][0], acc[mi][ni], 0, 0, 0); \
      acc[mi][ni] = __builtin_amdgcn_mfma_f32_16x16x32_bf16(afr[mi][1], bC[ni][1], acc[mi][ni], 0, 0, 0); \
    }                                                                                   \
  __builtin_amdgcn_s_setprio(0);                                                        \
  _Pragma("unroll") for (int mi = 0; mi < 4; ++mi) {                                    \
    afr[mi][0] = *(const bf16x8*)&sAc[abase + (mi + 4) * 1024 + aoff0];                 \
    afr[mi][1] = *(const bf16x8*)&sAc[abase + (mi + 4) * 1024 + aoff1];                 \
  }                                                                                     \
  __builtin_amdgcn_s_setprio(1);                                                        \
  _Pragma("unroll") for (int mi = 0; mi < 4; ++mi)                                      \
    _Pragma("unroll") for (int ni = 0; ni < 4; ++ni) {                                  \
      acc[mi + 4][ni] = __builtin_amdgcn_mfma_f32_16x16x32_bf16(afr[mi][0], bC[ni][0], acc[mi + 4][ni], 0, 0, 0); \
      acc[mi + 4][ni] = __builtin_amdgcn_mfma_f32_16x16x32_bf16(afr[mi][1], bC[ni][1], acc[mi + 4][ni], 0, 0, 0); \
    }                                                                                   \
  __builtin_amdgcn_s_setprio(0);                                                        \
  __syncthreads();                                                                      \
}

template <int EPI>
__global__ __launch_bounds__(512, 2) void gemm256(
    const bf16_t* __restrict__ A, int lda,
    const bf16_t* __restrict__ B0, int ldb,
    const float* __restrict__ bias,
    void* __restrict__ Cv, int ldc,
    int K, int ncols, int cpx,
    int rows_per_batch, long bstride)
{
  // 128KB: [0..16383]=sA0, [16384..32767]=sA1, whole array reused by epilogue
  __shared__ alignas(16) bf16_t smem[65536];
  bf16_t* const sA0 = smem;
  bf16_t* const sA1 = smem + 16384;

  // XCD-aware block swizzle (nwg % 8 == 0 guaranteed by caller)
  const int lin = blockIdx.x;
  const int wgid = (lin & 7) * cpx + (lin >> 3);
  const int row0 = (wgid / ncols) * 256;
  const int col0 = (wgid % ncols) * 256;

  const int tid = threadIdx.x;
  const int w = tid >> 6, l = tid & 63;
  const int wr = w >> 2, wc = w & 3;          // wave grid 2 (M) x 4 (N)
  const int llo = l & 15, lhi = l >> 4;
  const int x7 = llo & 7;

  const bf16_t* Bm = B0 + (long)(row0 / rows_per_batch) * bstride;
  const bf16_t* Bp = Bm + (long)(col0 + wc * 64 + llo) * ldb + lhi * 8;

  // A staging: chunk c = i*512 + tid; row = c>>3, LDS linear,
  // global source k-chunk pre-swizzled (involution kq ^ (row&7)).
  long a_off[4];
#pragma unroll
  for (int i = 0; i < 4; ++i) {
    int c = i * 512 + tid;
    int r = c >> 3;
    int kqs = (c & 7) ^ (r & 7);
    a_off[i] = (long)(row0 + r) * lda + kqs * 8;
  }
  const int dst8 = tid * 8;

  // ds_read addressing (element offsets into a 16384-elem A buffer):
  const int aoff0 = ((lhi)     ^ x7) * 8;
  const int aoff1 = ((lhi + 4) ^ x7) * 8;
  const int abase = (wr * 128 + llo) * 64;

  f32x4 acc[8][4] = {};
  bf16x8 bfrA[4][2], bfrB[4][2];
  const int NT = K >> 6;   // NT even, >= 4

  // prologue: stage A tile 0, load B tile 0 regs; syncthreads drains all
  gload_lds16(A + a_off[0], &sA0[dst8]);
  gload_lds16(A + a_off[1], &sA0[4096 + dst8]);
  gload_lds16(A + a_off[2], &sA0[8192 + dst8]);
  gload_lds16(A + a_off[3], &sA0[12288 + dst8]);
  LOADB(bfrA, 0L);
  __syncthreads();

  int t = 0;
  for (; t + 2 < NT; t += 2) {
    TILE1(sA0, sA1, bfrA, bfrB, (long)(t + 1) * 64, 1);
    TILE1(sA1, sA0, bfrB, bfrA, (long)(t + 2) * 64, 1);
  }
  TILE1(sA0, sA1, bfrA, bfrB, (long)(NT - 1) * 64, 1);
  TILE1(sA1, sA0, bfrB, bfrA, 0L, 0);

  // epilogue: C/D layout col=lane&15, row=(lane>>4)*4+j (verified)
  if constexpr (EPI == 1) {
    // bf16 out: acc -> LDS (XOR-chunk swizzled) -> vectorized 16B stores
#pragma unroll
    for (int ni = 0; ni < 4; ++ni) {
      const int cc = wc * 64 + ni * 16 + llo;
      const int gcol = col0 + cc;
      const float bz = bias[gcol];
      const bool doRelu = gcol < 2048;
#pragma unroll
      for (int mi = 0; mi < 8; ++mi) {
#pragma unroll
        for (int j = 0; j < 4; ++j) {
          const int rr = wr * 128 + mi * 16 + lhi * 4 + j;
          float v = acc[mi][ni][j] + bz;
          if (doRelu) v = fmaxf(v, 0.f) * 0.125f;
          smem[rr * 256 + (((cc >> 3) ^ (rr & 31)) << 3) + (cc & 7)] = (bf16_t)v;
        }
      }
    }
    __syncthreads();
    const int r = tid >> 1, half = tid & 1;
    bf16_t* outp = (bf16_t*)Cv + (long)(row0 + r) * ldc + col0;
#pragma unroll
    for (int k = 0; k < 16; ++k) {
      const int c = half * 16 + k;
      bf16x8 vv = *(const bf16x8*)&smem[r * 256 + ((c ^ (r & 31)) << 3)];
      *(bf16x8*)(outp + c * 8) = vv;
    }
  } else {
    // fp32 out, direct stores
#pragma unroll
    for (int ni = 0; ni < 4; ++ni) {
      const int gcol = col0 + wc * 64 + ni * 16 + llo;
      const float bz = bias[gcol];
#pragma unroll
      for (int mi = 0; mi < 8; ++mi) {
        const int grow0 = row0 + wr * 128 + mi * 16 + lhi * 4;
#pragma unroll
        for (int j = 0; j < 4; ++j)
          ((float*)Cv)[(long)(grow0 + j) * ldc + gcol] = acc[mi][ni][j] + bz;
      }
    }
  }
}

// ---------------- kv partial: kv[b,h,m,d] = sum_s K'[b,s,h,m]*V[b,s,h,d] ----------------
__global__ __launch_bounds__(256) void kv_partial(
    const bf16_t* __restrict__ QKV, float* __restrict__ kvpart)
{
  int bh = blockIdx.x;
  int split = blockIdx.y;
  int b = bh >> 4, h = bh & 15;
  __shared__ alignas(16) bf16_t Kt[64 * 32];
  __shared__ alignas(16) bf16_t Vt[64 * 32];
  int t = threadIdx.x;
  int wv = t >> 6, lane = t & 63, lhi = lane >> 4, llo = lane & 15;
  int r = t >> 3;
  int c = (t & 7) * 8;
  f32x4 acc[4] = {};
  long rowbase = ((long)b * 4096 + split * 512) * 3072 + h * 64 + c;
  for (int sc = 0; sc < 16; ++sc) {
    long off = rowbase + (long)(sc * 32 + r) * 3072;
    bf16x8 kk = *(const bf16x8*)(QKV + off + 1024);
    bf16x8 vvv = *(const bf16x8*)(QKV + off + 2048);
#pragma unroll
    for (int j = 0; j < 8; ++j) {
      Kt[(c + j) * 32 + r] = kk[j];
      Vt[(c + j) * 32 + r] = vvv[j];
    }
    __syncthreads();
    bf16x8 a = *(const bf16x8*)&Kt[(wv * 16 + llo) * 32 + lhi * 8];
#pragma unroll
    for (int ni = 0; ni < 4; ++ni) {
      bf16x8 bb = *(const bf16x8*)&Vt[(ni * 16 + llo) * 32 + lhi * 8];
      acc[ni] = __builtin_amdgcn_mfma_f32_16x16x32_bf16(a, bb, acc[ni], 0, 0, 0);
    }
    __syncthreads();
  }
#pragma unroll
  for (int ni = 0; ni < 4; ++ni)
#pragma unroll
    for (int j = 0; j < 4; ++j) {
      int m = wv * 16 + lhi * 4 + j;
      int d = ni * 16 + llo;
      kvpart[((long)split * 64 + bh) * 4096 + m * 64 + d] = acc[ni][j];
    }
}

__global__ void kv_reduce(const float* __restrict__ part, float* __restrict__ kv) {
  int i = blockIdx.x * 256 + threadIdx.x;
  float s = 0.f;
#pragma unroll
  for (int sp = 0; sp < 8; ++sp) s += part[sp * 262144 + i];
  kv[i] = s;
}

// ---------------- WcombT[b][n][h*64+m] = sum_d kv[b,h,m,d] * Wo[n][h*64+d] ----------------
__global__ __launch_bounds__(256) void wcombt_kernel(
    const float* __restrict__ kv, const float* __restrict__ Wo,
    bf16_t* __restrict__ WcT)
{
  int nt = blockIdx.x, h = blockIdx.y, b = blockIdx.z;
  __shared__ float kvs[4096];
  int t = threadIdx.x;
  for (int i = t * 4; i < 4096; i += 1024)
    *(f32x4*)&kvs[i] = *(const f32x4*)&kv[((long)b * 16 + h) * 4096 + i];
  __syncthreads();
  int n = nt * 128 + (t >> 1);
  int mh = (t & 1) * 32;
  f32x4 wo[16];
#pragma unroll
  for (int dd = 0; dd < 16; ++dd) wo[dd] = *(const f32x4*)&Wo[(long)n * 1024 + h * 64 + dd * 4];
  for (int m = mh; m < mh + 32; ++m) {
    f32x4 s = {0.f, 0.f, 0.f, 0.f};
#pragma unroll
    for (int dd = 0; dd < 16; ++dd)
      s += (*(const f32x4*)&kvs[m * 64 + dd * 4]) * wo[dd];
    WcT[((long)b * 1024 + n) * 1024 + h * 64 + m] = (bf16_t)(s[0] + s[1] + s[2] + s[3]);
  }
}

// ---------------- launch ----------------
extern "C" void kernel_launch(void* const* d_in, const int* in_sizes, int n_in,
                              void* d_out, int out_size, void* d_ws, size_t ws_size,
                              hipStream_t stream) {
  (void)in_sizes; (void)n_in; (void)out_size; (void)ws_size;
  const float* x  = (const float*)d_in[0];
  const float* Wq = (const float*)d_in[1];
  const float* bq = (const float*)d_in[2];
  const float* Wk = (const float*)d_in[3];
  const float* bk = (const float*)d_in[4];
  const float* Wv = (const float*)d_in[5];
  const float* bv = (const float*)d_in[6];
  const float* Wo = (const float*)d_in[7];
  const float* bo = (const float*)d_in[8];
  const float* P  = (const float*)d_in[9];
  float* out = (float*)d_out;

  char* ws = (char*)d_ws;
  bf16_t* xb     = (bf16_t*)(ws + 0);            // 32 MB
  bf16_t* QKV    = (bf16_t*)(ws + 33554432);     // 96 MB
  bf16_t* Wcat   = (bf16_t*)(ws + 134217728);    // 6 MB
  float*  bcat   = (float*) (ws + 140509184);    // 12 KB
  float*  kvpart = (float*) (ws + 140521472);    // 8 MB
  float*  kvbuf  = (float*) (ws + 148910080);    // 1 MB
  bf16_t* WcT    = (bf16_t*)(ws + 149958656);    // 8 MB

  // 1. casts + weight prep
  cast_f32_bf16<<<8192, 256, 0, stream>>>(x, xb, 2097152);
  cast_f32_bf16<<<512, 256, 0, stream>>>(Wv, Wcat + (size_t)2048 * 1024, 131072);
  copy_f32<<<4, 256, 0, stream>>>(bv, bcat + 2048, 1024);
  prep_wqk<<<256, 256, 0, stream>>>(Wq, bq, Wk, bk, P, Wcat, bcat);

  // 2. fused Q'/K'/V GEMM: [16384,1024] x [3072,1024]^T -> [16384,3072]
  //    grid 64 x 12 = 768 blocks (768 % 8 == 0), cpx = 96
  gemm256<1><<<768, 512, 0, stream>>>(
      xb, 1024, Wcat, 1024, bcat, QKV, 3072, 1024, 12, 96, 1 << 30, 0);

  // 3. kv = K'^T @ V per (b,h), 8-way split over s, then reduce
  kv_partial<<<dim3(64, 8), 256, 0, stream>>>(QKV, kvpart);
  kv_reduce<<<1024, 256, 0, stream>>>(kvpart, kvbuf);

  // 4. fold kv into Wo: WcombT per batch
  wcombt_kernel<<<dim3(8, 16, 4), 256, 0, stream>>>(kvbuf, Wo, WcT);

  // 5. out = Q' @ WcombT[b]^T + bo  (fp32 out)
  //    grid 64 x 4 = 256 blocks, cpx = 32
  gemm256<2><<<256, 512, 0, stream>>>(
      QKV, 3072, WcT, 1024, bo, out, 1024, 1024, 4, 32, 4096, (long)1024 * 1024);
}

// Round 6
// 243.804 us; speedup vs baseline: 1.3623x; 1.3623x over previous
//
#include <hip/hip_runtime.h>
#include <hip/hip_bf16.h>
#include <cstdint>

typedef __bf16 bf16_t;
typedef bf16_t bf16x8 __attribute__((ext_vector_type(8)));
typedef float f32x4 __attribute__((ext_vector_type(4)));

// B=4, S=4096, DIM=1024, H=16, HD=64, M=64
// QKV layout: [16384][3072] bf16, cols 0-1023 = Q', 1024-2047 = K', 2048-3071 = V

__device__ __forceinline__ void gload_lds16(const bf16_t* g, bf16_t* l) {
  __builtin_amdgcn_global_load_lds(
      (const __attribute__((address_space(1))) uint32_t*)g,
      (__attribute__((address_space(3))) uint32_t*)l, 16, 0, 0);
}

// ---------------- cast fp32 -> bf16 (vectorized, 8 elems/thread) ----------------
__global__ void cast_f32_bf16(const float* __restrict__ in, bf16_t* __restrict__ out, int n8) {
  int i = blockIdx.x * 256 + threadIdx.x;
  if (i < n8) {
    const f32x4* p = (const f32x4*)(in + (long)i * 8);
    f32x4 a = p[0], b = p[1];
    bf16x8 o;
#pragma unroll
    for (int j = 0; j < 4; ++j) { o[j] = (bf16_t)a[j]; o[j + 4] = (bf16_t)b[j]; }
    *(bf16x8*)(out + (long)i * 8) = o;
  }
}

__global__ void copy_f32(const float* __restrict__ in, float* __restrict__ out, int n) {
  int i = blockIdx.x * 256 + threadIdx.x;
  if (i < n) out[i] = in[i];
}

// ---------------- fold P into Wq/Wk:  WQP[h*64+m][k] = sum_d P[h][m][d]*W[h*64+d][k] ----------------
__global__ __launch_bounds__(256) void prep_wqk(
    const float* __restrict__ Wq, const float* __restrict__ bq,
    const float* __restrict__ Wk, const float* __restrict__ bk,
    const float* __restrict__ P,
    bf16_t* __restrict__ Wcat, float* __restrict__ bcat)
{
  int bid = blockIdx.x;
  int qk = bid >> 7, h = (bid >> 3) & 15, kt = bid & 7;
  const float* W = qk ? Wk : Wq;
  const float* bias = qk ? bk : bq;
  __shared__ float Pl[64 * 64];
  __shared__ float Wlt[128 * 68];
  int t = threadIdx.x;
  int k0 = kt * 128;
  for (int i = t * 4; i < 4096; i += 1024)
    *(f32x4*)&Pl[i] = *(const f32x4*)&P[h * 4096 + i];
  for (int fi = t; fi < 2048; fi += 256) {
    int row = fi >> 5;
    int c4 = fi & 31;
    f32x4 w = *(const f32x4*)&W[(long)(h * 64 + row) * 1024 + k0 + c4 * 4];
#pragma unroll
    for (int j = 0; j < 4; ++j) Wlt[(c4 * 4 + j) * 68 + row] = w[j];
  }
  __syncthreads();
  int kloc = t >> 1;
  int mh = (t & 1) * 32;
  for (int m = mh; m < mh + 32; ++m) {
    f32x4 s = {0.f, 0.f, 0.f, 0.f};
#pragma unroll
    for (int dd = 0; dd < 16; ++dd)
      s += (*(const f32x4*)&Pl[m * 64 + dd * 4]) * (*(const f32x4*)&Wlt[kloc * 68 + dd * 4]);
    float a = s[0] + s[1] + s[2] + s[3];
    Wcat[(long)(qk * 1024 + h * 64 + m) * 1024 + k0 + kloc] = (bf16_t)a;
  }
  if (kt == 0 && t < 64) {
    float a = 0.f;
    for (int d = 0; d < 64; ++d) a += Pl[t * 64 + d] * bias[h * 64 + d];
    bcat[qk * 1024 + h * 64 + t] = a;
  }
}

// ---------------- 256x256 GEMM, BK=64, 8 waves, 4-phase pipelined schedule -------
// C[M,N] = A[M,K] @ B[N,K]^T + bias.  EPI=1: bf16 out, relu*0.125 for gcol<2048.
// EPI=2: fp32 out.
//
// LDS: per matrix 4 k-half slots (parity x khalf, 16KB each). Slot layout packs
// rows 0-127 and 128-255 into [128 rows][8 chunks] with chunk = k-chunk + 4*hi,
// XOR-involution chunk^(row&7) on BOTH global source and ds_read (r1 algebra,
// measured 0 conflicts). Per phase: frag ds_reads for NEXT phase + 1 stage unit
// + 16 MFMA; counted vmcnt(2) at ph1/ph3 ends retires units issued 3 phases ago.
#define VMW(N) asm volatile("s_waitcnt vmcnt(" #N ")" ::: "memory")
#define SBAR() __builtin_amdgcn_s_barrier()

#define AFRAG(dst, P, KH, MIB)                                                      \
  _Pragma("unroll") for (int i = 0; i < 4; ++i)                                     \
    dst[i] = *(const bf16x8*)&smem[(P)*16384 + (KH)*8192 + ((MIB)+i)*1024 + llo64 + aoffA];

#define BFRAG(dst, P, KH)                                                           \
  _Pragma("unroll") for (int n = 0; n < 4; ++n)                                     \
    dst[n] = *(const bf16x8*)&smem[32768 + (P)*16384 + (KH)*8192 + bbase + n*1024 + boffB];

#define STAGE_A(P, KH, KOFF) {                                                      \
  gload_lds16(A + a_off0 + (KOFF) + (KH)*32, &smem[(P)*16384 + (KH)*8192 + dst8]);  \
  gload_lds16(A + a_off1 + (KOFF) + (KH)*32, &smem[(P)*16384 + (KH)*8192 + 4096 + dst8]); }

#define STAGE_B(P, KH, KOFF) {                                                      \
  gload_lds16(Bm + b_off0 + (KOFF) + (KH)*32, &smem[32768 + (P)*16384 + (KH)*8192 + dst8]); \
  gload_lds16(Bm + b_off1 + (KOFF) + (KH)*32, &smem[32768 + (P)*16384 + (KH)*8192 + 4096 + dst8]); }

#define MFMA_BLK(MIB, AF, BF)                                                       \
  __builtin_amdgcn_s_setprio(1);                                                    \
  _Pragma("unroll") for (int mi = 0; mi < 4; ++mi)                                  \
    _Pragma("unroll") for (int ni = 0; ni < 4; ++ni)                                \
      acc[(MIB)+mi][ni] = __builtin_amdgcn_mfma_f32_16x16x32_bf16(AF[mi], BF[ni], acc[(MIB)+mi][ni], 0, 0, 0); \
  __builtin_amdgcn_s_setprio(0);

// Phase bodies. Frag flow: PH1 mfma(afr0,bfr0)+read afr1(k0,mi4-7)+stage A(k0,next);
// PH2 mfma(afr1,bfr0)+read bfr1(k1),afr0(k1,mi0-3)+stage B(k0,next);
// PH3 mfma(afr0,bfr1)+read afr1(k1,mi4-7)+stage A(k1,next);
// PH4 mfma(afr1,bfr1)+read bfr0,afr0 of NEXT tile k0+stage B(k1,next).
#define PH1(P, Q, KOFF, STG, WN) {                                                  \
  AFRAG(afr1, P, 0, 4);                                                             \
  if (STG) STAGE_A(Q, 0, KOFF);                                                     \
  MFMA_BLK(0, afr0, bfr0);                                                          \
  VMW(WN); SBAR(); }

#define PH2(P, Q, KOFF, STG) {                                                      \
  BFRAG(bfr1, P, 1); AFRAG(afr0, P, 1, 0);                                          \
  if (STG) STAGE_B(Q, 0, KOFF);                                                     \
  MFMA_BLK(4, afr1, bfr0);                                                          \
  SBAR(); }

#define PH3(P, Q, KOFF, STG, WN) {                                                  \
  AFRAG(afr1, P, 1, 4);                                                             \
  if (STG) STAGE_A(Q, 1, KOFF);                                                     \
  MFMA_BLK(0, afr0, bfr1);                                                          \
  VMW(WN); SBAR(); }

#define PH4(P, Q, KOFF, STG, LAST) {                                                \
  if (!(LAST)) { BFRAG(bfr0, Q, 0); AFRAG(afr0, Q, 0, 0); }                         \
  if (STG) STAGE_B(Q, 1, KOFF);                                                     \
  MFMA_BLK(4, afr1, bfr1);                                                          \
  if (!(LAST)) SBAR(); }

template <int EPI>
__global__ __launch_bounds__(512, 2) void gemm256(
    const bf16_t* __restrict__ A, int lda,
    const bf16_t* __restrict__ B0, int ldb,
    const float* __restrict__ bias,
    void* __restrict__ Cv, int ldc,
    int K, int ncols, int cpx,
    int rows_per_batch, long bstride)
{
  __shared__ alignas(16) bf16_t smem[65536];   // A: 4x8192 slots, B: +32768

  // XCD-aware block swizzle (nwg % 8 == 0 guaranteed by caller)
  const int lin = blockIdx.x;
  const int wgid = (lin & 7) * cpx + (lin >> 3);
  const int row0 = (wgid / ncols) * 256;
  const int col0 = (wgid % ncols) * 256;

  const int tid = threadIdx.x;
  const int w = tid >> 6, l = tid & 63;
  const int wr = w >> 2, wc = w & 3;          // wave grid 2 (M) x 4 (N)
  const int llo = l & 15, lhi = l >> 4;
  const int x7 = llo & 7;

  const bf16_t* Bm = B0 + (long)(row0 / rows_per_batch) * bstride;

  // staging source offsets: unit = 256 rows x 32 k, stored as [rho=row&127][8 chunks],
  // chunk c8 = kq + 4*(row>>7), source pre-swizzled with involution c8 ^ (rho&7).
  long a_off0, a_off1, b_off0, b_off1;
  {
    int c0 = tid, c1 = 512 + tid;
    int r0 = c0 >> 3, cc0 = (c0 & 7) ^ (r0 & 7);
    int r1 = c1 >> 3, cc1 = (c1 & 7) ^ (r1 & 7);
    int srow0 = r0 + ((cc0 >> 2) << 7), skq0 = cc0 & 3;
    int srow1 = r1 + ((cc1 >> 2) << 7), skq1 = cc1 & 3;
    a_off0 = (long)(row0 + srow0) * lda + skq0 * 8;
    a_off1 = (long)(row0 + srow1) * lda + skq1 * 8;
    b_off0 = (long)(col0 + srow0) * ldb + skq0 * 8;
    b_off1 = (long)(col0 + srow1) * ldb + skq1 * 8;
  }
  const int dst8 = tid * 8;

  // ds_read addressing: row-in-slot rho = mi*16+llo (A) / (wc&1)*64+ni*16+llo (B);
  // chunk = (lhi + 4*hi) ^ (rho&7), hi = wr (A) / wc>>1 (B).
  const int llo64 = llo * 64;
  const int aoffA = ((lhi + 4 * wr) ^ x7) * 8;
  const int bbase = (wc & 1) * 4096 + llo * 64;
  const int boffB = ((lhi + 4 * (wc >> 1)) ^ x7) * 8;

  f32x4 acc[8][4] = {};
  bf16x8 afr0[4], afr1[4], bfr0[4], bfr1[4];
  const int NT = K >> 6;   // even, >= 4

  // prologue: stage tile0 units in order Ak0,Bk0,Ak1,Bk1; retire k0; read first frags
  STAGE_A(0, 0, 0L); STAGE_B(0, 0, 0L);
  STAGE_A(0, 1, 0L); STAGE_B(0, 1, 0L);
  VMW(4); SBAR();
  BFRAG(bfr0, 0, 0); AFRAG(afr0, 0, 0, 0);

  int t = 0;
  for (; t < NT - 2; t += 2) {
    const long k1 = (long)(t + 1) * 64, k2 = (long)(t + 2) * 64;
    PH1(0, 1, k1, 1, 2); PH2(0, 1, k1, 1); PH3(0, 1, k1, 1, 2); PH4(0, 1, k1, 1, 0);
    PH1(1, 0, k2, 1, 2); PH2(1, 0, k2, 1); PH3(1, 0, k2, 1, 2); PH4(1, 0, k2, 1, 0);
  }
  {  // tile NT-2 (parity 0), stages tile NT-1
    const long kL = (long)(NT - 1) * 64;
    PH1(0, 1, kL, 1, 2); PH2(0, 1, kL, 1); PH3(0, 1, kL, 1, 2); PH4(0, 1, kL, 1, 0);
  }
  {  // tile NT-1 (parity 1), no staging; vmcnt(0) drains remaining k1 units
    PH1(1, 0, 0L, 0, 0); PH2(1, 0, 0L, 0); PH3(1, 0, 0L, 0, 0); PH4(1, 0, 0L, 0, 1);
  }

  // epilogue: C/D layout col=lane&15, row=(lane>>4)*4+j (verified)
#pragma unroll
  for (int ni = 0; ni < 4; ++ni) {
    const int gcol = col0 + wc * 64 + ni * 16 + llo;
    const float bz = bias[gcol];
#pragma unroll
    for (int mi = 0; mi < 8; ++mi) {
      const int grow0 = row0 + wr * 128 + mi * 16 + lhi * 4;
#pragma unroll
      for (int j = 0; j < 4; ++j) {
        float v = acc[mi][ni][j] + bz;
        if constexpr (EPI == 1) { if (gcol < 2048) v = fmaxf(v, 0.f) * 0.125f; }
        if constexpr (EPI == 2)
          ((float*)Cv)[(long)(grow0 + j) * ldc + gcol] = v;
        else
          ((bf16_t*)Cv)[(long)(grow0 + j) * ldc + gcol] = (bf16_t)v;
      }
    }
  }
}

// ---------------- kv partial: kv[b,h,m,d] = sum_s K'[b,s,h,m]*V[b,s,h,d] ----------------
__global__ __launch_bounds__(256) void kv_partial(
    const bf16_t* __restrict__ QKV, float* __restrict__ kvpart)
{
  int bh = blockIdx.x;
  int split = blockIdx.y;
  int b = bh >> 4, h = bh & 15;
  __shared__ alignas(16) bf16_t Kt[64 * 32];
  __shared__ alignas(16) bf16_t Vt[64 * 32];
  int t = threadIdx.x;
  int wv = t >> 6, lane = t & 63, lhi = lane >> 4, llo = lane & 15;
  int r = t >> 3;
  int c = (t & 7) * 8;
  f32x4 acc[4] = {};
  long rowbase = ((long)b * 4096 + split * 512) * 3072 + h * 64 + c;
  for (int sc = 0; sc < 16; ++sc) {
    long off = rowbase + (long)(sc * 32 + r) * 3072;
    bf16x8 kk = *(const bf16x8*)(QKV + off + 1024);
    bf16x8 vvv = *(const bf16x8*)(QKV + off + 2048);
#pragma unroll
    for (int j = 0; j < 8; ++j) {
      Kt[(c + j) * 32 + r] = kk[j];
      Vt[(c + j) * 32 + r] = vvv[j];
    }
    __syncthreads();
    bf16x8 a = *(const bf16x8*)&Kt[(wv * 16 + llo) * 32 + lhi * 8];
#pragma unroll
    for (int ni = 0; ni < 4; ++ni) {
      bf16x8 bb = *(const bf16x8*)&Vt[(ni * 16 + llo) * 32 + lhi * 8];
      acc[ni] = __builtin_amdgcn_mfma_f32_16x16x32_bf16(a, bb, acc[ni], 0, 0, 0);
    }
    __syncthreads();
  }
#pragma unroll
  for (int ni = 0; ni < 4; ++ni)
#pragma unroll
    for (int j = 0; j < 4; ++j) {
      int m = wv * 16 + lhi * 4 + j;
      int d = ni * 16 + llo;
      kvpart[((long)split * 64 + bh) * 4096 + m * 64 + d] = acc[ni][j];
    }
}

__global__ void kv_reduce(const float* __restrict__ part, float* __restrict__ kv) {
  int i = blockIdx.x * 256 + threadIdx.x;
  float s = 0.f;
#pragma unroll
  for (int sp = 0; sp < 8; ++sp) s += part[sp * 262144 + i];
  kv[i] = s;
}

// ---------------- WcombT[b][n][h*64+m] = sum_d kv[b,h,m,d] * Wo[n][h*64+d] ----------------
__global__ __launch_bounds__(256) void wcombt_kernel(
    const float* __restrict__ kv, const float* __restrict__ Wo,
    bf16_t* __restrict__ WcT)
{
  int nt = blockIdx.x, h = blockIdx.y, b = blockIdx.z;
  __shared__ float kvs[4096];
  int t = threadIdx.x;
  for (int i = t * 4; i < 4096; i += 1024)
    *(f32x4*)&kvs[i] = *(const f32x4*)&kv[((long)b * 16 + h) * 4096 + i];
  __syncthreads();
  int n = nt * 128 + (t >> 1);
  int mh = (t & 1) * 32;
  f32x4 wo[16];
#pragma unroll
  for (int dd = 0; dd < 16; ++dd) wo[dd] = *(const f32x4*)&Wo[(long)n * 1024 + h * 64 + dd * 4];
  for (int m = mh; m < mh + 32; ++m) {
    f32x4 s = {0.f, 0.f, 0.f, 0.f};
#pragma unroll
    for (int dd = 0; dd < 16; ++dd)
      s += (*(const f32x4*)&kvs[m * 64 + dd * 4]) * wo[dd];
    WcT[((long)b * 1024 + n) * 1024 + h * 64 + m] = (bf16_t)(s[0] + s[1] + s[2] + s[3]);
  }
}

// ---------------- launch ----------------
extern "C" void kernel_launch(void* const* d_in, const int* in_sizes, int n_in,
                              void* d_out, int out_size, void* d_ws, size_t ws_size,
                              hipStream_t stream) {
  (void)in_sizes; (void)n_in; (void)out_size; (void)ws_size;
  const float* x  = (const float*)d_in[0];
  const float* Wq = (const float*)d_in[1];
  const float* bq = (const float*)d_in[2];
  const float* Wk = (const float*)d_in[3];
  const float* bk = (const float*)d_in[4];
  const float* Wv = (const float*)d_in[5];
  const float* bv = (const float*)d_in[6];
  const float* Wo = (const float*)d_in[7];
  const float* bo = (const float*)d_in[8];
  const float* P  = (const float*)d_in[9];
  float* out = (float*)d_out;

  char* ws = (char*)d_ws;
  bf16_t* xb     = (bf16_t*)(ws + 0);            // 32 MB
  bf16_t* QKV    = (bf16_t*)(ws + 33554432);     // 96 MB
  bf16_t* Wcat   = (bf16_t*)(ws + 134217728);    // 6 MB
  float*  bcat   = (float*) (ws + 140509184);    // 12 KB
  float*  kvpart = (float*) (ws + 140521472);    // 8 MB
  float*  kvbuf  = (float*) (ws + 148910080);    // 1 MB
  bf16_t* WcT    = (bf16_t*)(ws + 149958656);    // 8 MB

  // 1. casts + weight prep
  cast_f32_bf16<<<8192, 256, 0, stream>>>(x, xb, 2097152);
  cast_f32_bf16<<<512, 256, 0, stream>>>(Wv, Wcat + (size_t)2048 * 1024, 131072);
  copy_f32<<<4, 256, 0, stream>>>(bv, bcat + 2048, 1024);
  prep_wqk<<<256, 256, 0, stream>>>(Wq, bq, Wk, bk, P, Wcat, bcat);

  // 2. fused Q'/K'/V GEMM: [16384,1024] x [3072,1024]^T -> [16384,3072]
  //    grid 64 x 12 = 768 blocks (768 % 8 == 0), cpx = 96
  gemm256<1><<<768, 512, 0, stream>>>(
      xb, 1024, Wcat, 1024, bcat, QKV, 3072, 1024, 12, 96, 1 << 30, 0);

  // 3. kv = K'^T @ V per (b,h), 8-way split over s, then reduce
  kv_partial<<<dim3(64, 8), 256, 0, stream>>>(QKV, kvpart);
  kv_reduce<<<1024, 256, 0, stream>>>(kvpart, kvbuf);

  // 4. fold kv into Wo: WcombT per batch
  wcombt_kernel<<<dim3(8, 16, 4), 256, 0, stream>>>(kvbuf, Wo, WcT);

  // 5. out = Q' @ WcombT[b]^T + bo  (fp32 out)
  //    grid 64 x 4 = 256 blocks, cpx = 32
  gemm256<2><<<256, 512, 0, stream>>>(
      QKV, 3072, WcT, 1024, bo, out, 1024, 1024, 4, 32, 4096, (long)1024 * 1024);
}